// Round 6
// baseline (364.472 us; speedup 1.0000x reference)
//
#include <hip/hip_runtime.h>
#include <math.h>

#define BSZ 64
#define NPT 16384
#define SEG 16
#define NFPS 256
#define MAXPTS 2048
#define NTHREADS 256
#define KPT 8
#define NPAIR 4  // KPT/2 packed-f32 pairs

typedef __attribute__((ext_vector_type(2))) float f32x2;

// Packed f32 ops (VOP3P). Per-element IEEE round-to-nearest — bit-exact vs
// scalar v_add/v_mul, 2 points per instruction.
__device__ __forceinline__ f32x2 pk_add(f32x2 a, f32x2 b) {
    f32x2 d;
    asm("v_pk_add_f32 %0, %1, %2" : "=v"(d) : "v"(a), "v"(b));
    return d;
}
__device__ __forceinline__ f32x2 pk_mul(f32x2 a, f32x2 b) {
    f32x2 d;
    asm("v_pk_mul_f32 %0, %1, %2" : "=v"(d) : "v"(a), "v"(b));
    return d;
}

// One step of wave64 max-reduce-to-lane63. bound_ctrl=1 shifts in 0.0f, the
// identity here (all reduced values >= 0).
template <int CTRL>
__device__ __forceinline__ float dpp_max_f32(float v) {
    const int o = __builtin_amdgcn_update_dpp(0, __float_as_int(v), CTRL, 0xf, 0xf, true);
    return fmaxf(v, __int_as_float(o));
}

__global__ __launch_bounds__(NTHREADS) void fps_part_kernel(const float* __restrict__ x,
                                                            float* __restrict__ out) {
    const int blk = blockIdx.x;          // b*16 + s
    const int b = blk >> 4;
    const int s = blk & 15;
    const int tid = threadIdx.x;
    const int lane = tid & 63;
    const int wave = tid >> 6;

    __shared__ float4 pts[MAXPTS];
    __shared__ int wcnt[4][4];           // [wave][j]
    __shared__ float4 rb[2][4];          // double-buffered per-wave winner {x,y,z,val}

    // ---------------- Phase 1: stable compaction of points with label==s ----------------
    const float4* x4 = (const float4*)x + (size_t)b * NPT;
    const float fs = (float)s;
    int total = 0;  // running count, same value in every thread

    for (int mc = 0; mc < 16; ++mc) {
        float4 p[4];
        bool pred[4];
        int lanePre[4];
        #pragma unroll
        for (int j = 0; j < 4; ++j)
            p[j] = x4[(mc * 4 + j) * NTHREADS + tid];
        #pragma unroll
        for (int j = 0; j < 4; ++j) {
            pred[j] = (p[j].w == fs);
            const unsigned long long m = __ballot(pred[j]);
            lanePre[j] = __builtin_amdgcn_mbcnt_hi((unsigned)(m >> 32),
                         __builtin_amdgcn_mbcnt_lo((unsigned)m, 0));
            if (lane == 0) wcnt[wave][j] = __popcll(m);
        }
        __syncthreads();
        #pragma unroll
        for (int j = 0; j < 4; ++j) {
            const int w0 = wcnt[0][j], w1 = wcnt[1][j], w2 = wcnt[2][j], w3 = wcnt[3][j];
            int base = total;
            if (wave > 0) base += w0;
            if (wave > 1) base += w1;
            if (wave > 2) base += w2;
            if (pred[j]) {
                const int pos = base + lanePre[j];
                if (pos < MAXPTS) pts[pos] = p[j];
            }
            total += w0 + w1 + w2 + w3;
        }
        __syncthreads();
    }

    const int count = (total < MAXPTS) ? total : MAXPTS;
    const size_t gp_base = (size_t)blk * NFPS * 3;
    const size_t mask_off = (size_t)BSZ * SEG * NFPS * 3 + (size_t)blk;

    if (count < NFPS) {
        for (int i = tid; i < NFPS * 3; i += NTHREADS) out[gp_base + i] = 0.0f;
        if (tid == 0) out[mask_off] = 0.0f;
        return;
    }
    if (tid == 0) out[mask_off] = 1.0f;

    // ---------------- Phase 2: FPS over compacted points ----------------
    const int cnt_s = __builtin_amdgcn_readfirstlane(count);
    const int pmax = (cnt_s + 511) >> 9;   // packed pairs actually populated (uniform)

    // Pair p holds compacted slots (2p)*256+tid and (2p+1)*256+tid.
    f32x2 xp[NPAIR], yp[NPAIR], zp[NPAIR], mdp[NPAIR];
    #pragma unroll
    for (int p = 0; p < NPAIR; ++p) {
        const int i0 = tid + ((2 * p) << 8);
        const int i1 = i0 + 256;
        const bool v0 = (i0 < count), v1 = (i1 < count);
        const float4 q0 = pts[v0 ? i0 : 0];
        const float4 q1 = pts[v1 ? i1 : 0];
        xp[p].x = q0.x; xp[p].y = q1.x;
        yp[p].x = q0.y; yp[p].y = q1.y;
        zp[p].x = q0.z; zp[p].y = q1.z;
        mdp[p].x = v0 ? INFINITY : -INFINITY;
        mdp[p].y = v1 ? INFINITY : -INFINITY;
    }

    float4 c = pts[0];  // cur_pt at t=0: first masked point (argmax(mask))
    for (int t = 0; t < NFPS; ++t) {
        if (tid < 3)
            out[gp_base + (size_t)t * 3 + tid] = (tid == 0) ? c.x : ((tid == 1) ? c.y : c.z);

        f32x2 ncx; ncx.x = -c.x; ncx.y = -c.x;
        f32x2 ncy; ncy.x = -c.y; ncy.y = -c.y;
        f32x2 ncz; ncz.x = -c.z; ncz.y = -c.z;

        float best = -INFINITY, bx = 0.0f, by = 0.0f, bz = 0.0f;
        #pragma unroll
        for (int p = 0; p < NPAIR; ++p) {
            if (p < pmax) {  // uniform scalar branch
                // Bit-exact: (dx*dx + dy*dy) + dz*dz, rn, no FMA.  a-b == a+(-b) exactly.
                const f32x2 dx = pk_add(xp[p], ncx);
                const f32x2 dy = pk_add(yp[p], ncy);
                const f32x2 dz = pk_add(zp[p], ncz);
                const f32x2 d = pk_add(pk_add(pk_mul(dx, dx), pk_mul(dy, dy)), pk_mul(dz, dz));
                f32x2 m;
                m.x = fminf(mdp[p].x, d.x);
                m.y = fminf(mdp[p].y, d.y);
                mdp[p] = m;
                // strict > keeps the first (lowest-slot) max within this lane
                if (m.x > best) { best = m.x; bx = xp[p].x; by = yp[p].x; bz = zp[p].x; }
                if (m.y > best) { best = m.y; bx = xp[p].y; by = yp[p].y; bz = zp[p].y; }
            }
        }

        // value-only wave reduce; keep the PRE-reduce local best for winner ident.
        const float mybest = best;
        best = dpp_max_f32<0x111>(best);  // row_shr:1
        best = dpp_max_f32<0x112>(best);  // row_shr:2
        best = dpp_max_f32<0x114>(best);  // row_shr:4
        best = dpp_max_f32<0x118>(best);  // row_shr:8
        best = dpp_max_f32<0x142>(best);  // row_bcast:15
        best = dpp_max_f32<0x143>(best);  // row_bcast:31
        const float wv = __int_as_float(__builtin_amdgcn_readlane(__float_as_int(best), 63));

        // winner lane = lowest lane whose ORIGINAL best equals the wave max.
        const unsigned long long wm = __ballot(mybest == wv);
        const int winlane = __ffsll(wm) - 1;   // uniform (SGPR)
        const float wx = __int_as_float(__builtin_amdgcn_readlane(__float_as_int(bx), winlane));
        const float wy = __int_as_float(__builtin_amdgcn_readlane(__float_as_int(by), winlane));
        const float wz = __int_as_float(__builtin_amdgcn_readlane(__float_as_int(bz), winlane));

        const int buf = t & 1;  // double-buffered scratch -> one barrier per iteration
        if (lane == 0) rb[buf][wave] = make_float4(wx, wy, wz, wv);
        __syncthreads();

        // cross-wave combine: strict > keeps lowest wave on ties
        const float4 r0 = rb[buf][0], r1 = rb[buf][1], r2 = rb[buf][2], r3 = rb[buf][3];
        const float4 b01 = (r1.w > r0.w) ? r1 : r0;
        const float4 b23 = (r3.w > r2.w) ? r3 : r2;
        c = (b23.w > b01.w) ? b23 : b01;
    }
}

extern "C" void kernel_launch(void* const* d_in, const int* in_sizes, int n_in,
                              void* d_out, int out_size, void* d_ws, size_t ws_size,
                              hipStream_t stream) {
    const float* x = (const float*)d_in[0];
    float* out = (float*)d_out;
    fps_part_kernel<<<BSZ * SEG, NTHREADS, 0, stream>>>(x, out);
}

// Round 7
// 352.866 us; speedup vs baseline: 1.0329x; 1.0329x over previous
//
#include <hip/hip_runtime.h>
#include <math.h>

#define BSZ 64
#define NPT 16384
#define SEG 16
#define NFPS 256
#define MAXPTS 2048
#define NLANES 64
#define NSLOT 32   // MAXPTS / NLANES points per lane
#define NPAIR 16   // NSLOT / 2 packed pairs

typedef __attribute__((ext_vector_type(2))) float f32x2;

// Packed f32 ops (VOP3P) — per-element IEEE rn, bit-exact vs scalar.
__device__ __forceinline__ f32x2 pk_add(f32x2 a, f32x2 b) {
    f32x2 d;
    asm("v_pk_add_f32 %0, %1, %2" : "=v"(d) : "v"(a), "v"(b));
    return d;
}
__device__ __forceinline__ f32x2 pk_mul(f32x2 a, f32x2 b) {
    f32x2 d;
    asm("v_pk_mul_f32 %0, %1, %2" : "=v"(d) : "v"(a), "v"(b));
    return d;
}

// u64 max with DPP-shifted partner (reduce-to-lane63 chain). bound_ctrl=1
// shifts in 0 == identity (keys >= 0). Hardware-verified in R3 (absmax 0).
template <int CTRL>
__device__ __forceinline__ unsigned long long dpp_max_u64(unsigned long long k) {
    const int lo = __builtin_amdgcn_update_dpp(0, (int)(unsigned)k, CTRL, 0xf, 0xf, true);
    const int hi = __builtin_amdgcn_update_dpp(0, (int)(unsigned)(k >> 32), CTRL, 0xf, 0xf, true);
    const unsigned long long ok = ((unsigned long long)(unsigned)hi << 32) | (unsigned)lo;
    return ok > k ? ok : k;
}

__global__ __launch_bounds__(NLANES, 1) void fps_part_kernel(const float* __restrict__ x,
                                                             float* __restrict__ out) {
    const int blk = blockIdx.x;          // b*16 + s
    const int b = blk >> 4;
    const int s = blk & 15;
    const int lane = threadIdx.x;        // single wave: tid == lane

    __shared__ float4 pts[MAXPTS];

    // ---------------- Phase 1: stable compaction (wave-coherent, no barriers) ----------------
    const float4* x4 = (const float4*)x + (size_t)b * NPT;
    const float fs = (float)s;
    const unsigned long long lanemask = (1ull << lane) - 1ull;
    int total = 0;

    for (int mc = 0; mc < 32; ++mc) {
        float4 p[8];
        #pragma unroll
        for (int j = 0; j < 8; ++j)
            p[j] = x4[(mc * 8 + j) * NLANES + lane];
        #pragma unroll
        for (int j = 0; j < 8; ++j) {
            const bool pred = (p[j].w == fs);
            const unsigned long long m = __ballot(pred);
            const int pos = total + __popcll(m & lanemask);
            if (pred && pos < MAXPTS) pts[pos] = p[j];
            total += __popcll(m);   // uniform -> SALU
        }
    }
    __syncthreads();  // single-wave: cheap; orders ds_writes vs ds_reads

    const int count = (total < MAXPTS) ? total : MAXPTS;
    const size_t gp_base = (size_t)blk * NFPS * 3;
    const size_t mask_off = (size_t)BSZ * SEG * NFPS * 3 + (size_t)blk;

    if (count < NFPS) {
        for (int i = lane; i < NFPS * 3; i += NLANES) out[gp_base + i] = 0.0f;
        if (lane == 0) out[mask_off] = 0.0f;
        return;
    }
    if (lane == 0) out[mask_off] = 1.0f;

    // ---------------- Phase 2: FPS, fully in-register, zero barriers ----------------
    const int cnt_s = __builtin_amdgcn_readfirstlane(count);
    const int pmax = (cnt_s + 127) >> 7;   // active pairs (uniform): ~8 for count~1024

    // Slot s holds compacted index s*64+lane (slot-major => order-preserving).
    f32x2 xp[NPAIR], yp[NPAIR], zp[NPAIR];
    float md[NSLOT];
    unsigned ni[NSLOT];                     // precomputed ~(global idx), loop-invariant
    const unsigned nlane = ~(unsigned)lane;
    #pragma unroll
    for (int p = 0; p < NPAIR; ++p) {
        const int i0 = (2 * p) * NLANES + lane;
        const int i1 = i0 + NLANES;
        const bool v0 = (i0 < count), v1 = (i1 < count);
        const float4 q0 = pts[v0 ? i0 : 0];
        const float4 q1 = pts[v1 ? i1 : 0];
        xp[p].x = q0.x; xp[p].y = q1.x;
        yp[p].x = q0.y; yp[p].y = q1.y;
        zp[p].x = q0.z; zp[p].y = q1.z;
        md[2 * p]     = v0 ? INFINITY : -INFINITY;
        md[2 * p + 1] = v1 ? INFINITY : -INFINITY;
        ni[2 * p]     = nlane - (unsigned)((2 * p) << 6);      // == ~(i0)
        ni[2 * p + 1] = nlane - (unsigned)((2 * p + 1) << 6);  // == ~(i1)
    }

    float4 c = pts[0];  // first masked point == argmax(mask)
    for (int t = 0; t < NFPS; ++t) {
        if (lane < 3)
            out[gp_base + (size_t)t * 3 + lane] = (lane == 0) ? c.x : ((lane == 1) ? c.y : c.z);

        f32x2 ncx; ncx.x = -c.x; ncx.y = -c.x;
        f32x2 ncy; ncy.x = -c.y; ncy.y = -c.y;
        f32x2 ncz; ncz.x = -c.z; ncz.y = -c.z;

        // 4 interleaved u64-key argmax chains (slot s -> chain s&3): short dep chains.
        // key = (bits(val)<<32) | ~idx ; u64 max == (max val, min idx) == np.argmax.
        unsigned long long k0 = 0, k1 = 0, k2 = 0, k3 = 0;  // 0 == identity (val>=0 or -inf loses)
        #pragma unroll
        for (int p = 0; p < NPAIR; ++p) {
            if (p < pmax) {  // uniform scalar branch
                // Bit-exact: (dx*dx + dy*dy) + dz*dz, rn, no FMA; a-b == a+(-b) exactly.
                const f32x2 dx = pk_add(xp[p], ncx);
                const f32x2 dy = pk_add(yp[p], ncy);
                const f32x2 dz = pk_add(zp[p], ncz);
                const f32x2 d = pk_add(pk_add(pk_mul(dx, dx), pk_mul(dy, dy)), pk_mul(dz, dz));
                const float m0 = fminf(md[2 * p], d.x);
                const float m1 = fminf(md[2 * p + 1], d.y);
                md[2 * p] = m0;
                md[2 * p + 1] = m1;
                // -inf slots pack to key with sign bit set? bits(-inf)=0xFF800000 is large
                // as unsigned -- mask them: valid slots have m >= 0 (sign bit clear).
                const unsigned b0 = __float_as_uint(m0);
                const unsigned b1 = __float_as_uint(m1);
                const unsigned long long kn0 =
                    (b0 & 0x80000000u) ? 0ull : (((unsigned long long)b0 << 32) | ni[2 * p]);
                const unsigned long long kn1 =
                    (b1 & 0x80000000u) ? 0ull : (((unsigned long long)b1 << 32) | ni[2 * p + 1]);
                if ((p & 1) == 0) {
                    if (kn0 > k0) k0 = kn0;
                    if (kn1 > k1) k1 = kn1;
                } else {
                    if (kn0 > k2) k2 = kn0;
                    if (kn1 > k3) k3 = kn1;
                }
            }
        }
        if (k1 > k0) k0 = k1;
        if (k3 > k2) k2 = k3;
        unsigned long long key = (k2 > k0) ? k2 : k0;

        // wave64 u64 max reduce to lane 63 (DPP, no LDS-unit latency)
        key = dpp_max_u64<0x111>(key);  // row_shr:1
        key = dpp_max_u64<0x112>(key);  // row_shr:2
        key = dpp_max_u64<0x114>(key);  // row_shr:4
        key = dpp_max_u64<0x118>(key);  // row_shr:8
        key = dpp_max_u64<0x142>(key);  // row_bcast:15
        key = dpp_max_u64<0x143>(key);  // row_bcast:31

        const unsigned keylo = (unsigned)__builtin_amdgcn_readlane((int)(unsigned)key, 63);
        const int idx = (int)(~keylo);  // uniform (SGPR): winner's compacted index
        c = pts[idx];                   // uniform-addr ds_read_b128 broadcast
    }
}

extern "C" void kernel_launch(void* const* d_in, const int* in_sizes, int n_in,
                              void* d_out, int out_size, void* d_ws, size_t ws_size,
                              hipStream_t stream) {
    const float* x = (const float*)d_in[0];
    float* out = (float*)d_out;
    fps_part_kernel<<<BSZ * SEG, NLANES, 0, stream>>>(x, out);
}

// Round 8
// 257.756 us; speedup vs baseline: 1.4140x; 1.3690x over previous
//
#include <hip/hip_runtime.h>
#include <math.h>

#define BSZ 64
#define NPT 16384
#define SEG 16
#define NFPS 256
#define MAXPTS 2048
#define NLANES 64

typedef __attribute__((ext_vector_type(2))) float f32x2;

// Packed f32 ops (VOP3P) — per-element IEEE rn, bit-exact vs scalar.
__device__ __forceinline__ f32x2 pk_add(f32x2 a, f32x2 b) {
    f32x2 d;
    asm("v_pk_add_f32 %0, %1, %2" : "=v"(d) : "v"(a), "v"(b));
    return d;
}
__device__ __forceinline__ f32x2 pk_mul(f32x2 a, f32x2 b) {
    f32x2 d;
    asm("v_pk_mul_f32 %0, %1, %2" : "=v"(d) : "v"(a), "v"(b));
    return d;
}

// One step of wave64 f32 max-reduce-to-lane63; bound_ctrl=1 shifts in 0.0f,
// the identity here (per-lane best >= 0 always: slot 0 of every lane is valid).
template <int CTRL>
__device__ __forceinline__ float dpp_max_f32(float v) {
    const int o = __builtin_amdgcn_update_dpp(0, __float_as_int(v), CTRL, 0xf, 0xf, true);
    return fmaxf(v, __int_as_float(o));
}

// Phase 2 with compile-time pair count P (covers count <= 128*P; extra slots = -inf).
template <int P>
__device__ __forceinline__ void fps_phase2(const float4* __restrict__ pts,
                                           float* __restrict__ out,
                                           size_t gp_base, int count, int lane) {
    f32x2 xp[P], yp[P], zp[P];
    float md[2 * P];
    #pragma unroll
    for (int p = 0; p < P; ++p) {
        const int i0 = (2 * p) * NLANES + lane;
        const int i1 = i0 + NLANES;
        const bool v0 = (i0 < count), v1 = (i1 < count);
        const float4 q0 = pts[v0 ? i0 : 0];
        const float4 q1 = pts[v1 ? i1 : 0];
        xp[p].x = q0.x; xp[p].y = q1.x;
        yp[p].x = q0.y; yp[p].y = q1.y;
        zp[p].x = q0.z; zp[p].y = q1.z;
        md[2 * p]     = v0 ? INFINITY : -INFINITY;
        md[2 * p + 1] = v1 ? INFINITY : -INFINITY;
    }

    float4 c = pts[0];  // first masked point == argmax(mask)
    for (int t = 0; t < NFPS; ++t) {
        if (lane < 3)
            out[gp_base + (size_t)t * 3 + lane] = (lane == 0) ? c.x : ((lane == 1) ? c.y : c.z);

        f32x2 ncx; ncx.x = -c.x; ncx.y = -c.x;
        f32x2 ncy; ncy.x = -c.y; ncy.y = -c.y;
        f32x2 ncz; ncz.x = -c.z; ncz.y = -c.z;

        // Pure value pass: dist (bit-exact (dx*dx+dy*dy)+dz*dz, rn, no FMA),
        // md update, running max into 4 independent accumulator chains.
        float a0 = -INFINITY, a1 = -INFINITY, a2 = -INFINITY, a3 = -INFINITY;
        #pragma unroll
        for (int p = 0; p < P; ++p) {
            const f32x2 dx = pk_add(xp[p], ncx);
            const f32x2 dy = pk_add(yp[p], ncy);
            const f32x2 dz = pk_add(zp[p], ncz);
            const f32x2 d = pk_add(pk_add(pk_mul(dx, dx), pk_mul(dy, dy)), pk_mul(dz, dz));
            const float m0 = fminf(md[2 * p], d.x);
            const float m1 = fminf(md[2 * p + 1], d.y);
            md[2 * p] = m0;
            md[2 * p + 1] = m1;
            if (p & 1) { a2 = fmaxf(a2, m0); a3 = fmaxf(a3, m1); }
            else       { a0 = fmaxf(a0, m0); a1 = fmaxf(a1, m1); }
        }
        float best = fmaxf(fmaxf(a0, a1), fmaxf(a2, a3));

        // wave64 value max (fmax/fmin return operand bits exactly -> wv is
        // bit-identical to the winning slot's md value)
        best = dpp_max_f32<0x111>(best);  // row_shr:1
        best = dpp_max_f32<0x112>(best);  // row_shr:2
        best = dpp_max_f32<0x114>(best);  // row_shr:4
        best = dpp_max_f32<0x118>(best);  // row_shr:8
        best = dpp_max_f32<0x142>(best);  // row_bcast:15
        best = dpp_max_f32<0x143>(best);  // row_bcast:31
        const float wv = __int_as_float(__builtin_amdgcn_readlane(__float_as_int(best), 63));

        // Rescan registers for the winner: lowest matching slot per lane
        // (descending overwrite chain), then lowest matching lane via ballot.
        int mslot = 0x7fff;
        #pragma unroll
        for (int sl = 2 * P - 1; sl >= 0; --sl)
            if (md[sl] == wv) mslot = sl;  // cmp+cndmask; last write = lowest slot

        const unsigned long long wm = __ballot(mslot != 0x7fff);
        const int winlane = __builtin_amdgcn_readfirstlane(__ffsll((long long)wm) - 1);
        const int wslot = __builtin_amdgcn_readlane(mslot, winlane);
        c = pts[wslot * NLANES + winlane];  // uniform-addr ds_read_b128 broadcast
    }
}

__global__ __launch_bounds__(NLANES, 1) void fps_part_kernel(const float* __restrict__ x,
                                                             float* __restrict__ out) {
    // XCD swizzle: all 16 segment-blocks of one batch share blockIdx%8 -> same
    // XCD L2 caches that batch's 256KB slice once (8 batches x 256KB = 2MB < 4MB L2).
    const int blk = blockIdx.x;
    const int xcd = blk & 7;
    const int grp = blk >> 3;            // 0..127
    const int b = (xcd << 3) | (grp >> 4);
    const int s = grp & 15;
    const int prob = b * SEG + s;        // logical problem id (output slot)
    const int lane = threadIdx.x;        // single wave

    __shared__ float4 pts[MAXPTS];

    // ---------------- Phase 1: stable compaction (wave-coherent, no barriers) ----------------
    const float4* x4 = (const float4*)x + (size_t)b * NPT;
    const float fs = (float)s;
    const unsigned long long lanemask = (1ull << lane) - 1ull;
    int total = 0;

    for (int mc = 0; mc < 32; ++mc) {
        float4 p[8];
        #pragma unroll
        for (int j = 0; j < 8; ++j)
            p[j] = x4[(mc * 8 + j) * NLANES + lane];
        #pragma unroll
        for (int j = 0; j < 8; ++j) {
            const bool pred = (p[j].w == fs);
            const unsigned long long m = __ballot(pred);
            const int pos = total + __popcll(m & lanemask);
            if (pred && pos < MAXPTS) pts[pos] = p[j];
            total += __popcll(m);   // uniform -> SALU
        }
    }
    __syncthreads();  // single wave: cheap; orders ds_writes vs ds_reads

    const int count = (total < MAXPTS) ? total : MAXPTS;
    const size_t gp_base = (size_t)prob * NFPS * 3;
    const size_t mask_off = (size_t)BSZ * SEG * NFPS * 3 + (size_t)prob;

    if (count < NFPS) {
        for (int i = lane; i < NFPS * 3; i += NLANES) out[gp_base + i] = 0.0f;
        if (lane == 0) out[mask_off] = 0.0f;
        return;
    }
    if (lane == 0) out[mask_off] = 1.0f;

    // ---------------- Phase 2: compile-time-specialized pair count ----------------
    const int cnt_s = __builtin_amdgcn_readfirstlane(count);
    const int pmax = (cnt_s + 127) >> 7;   // ceil(count/128); ~8-9 for count~1024

    if (pmax <= 8)       fps_phase2<8>(pts, out, gp_base, count, lane);
    else if (pmax == 9)  fps_phase2<9>(pts, out, gp_base, count, lane);
    else                 fps_phase2<16>(pts, out, gp_base, count, lane);
}

extern "C" void kernel_launch(void* const* d_in, const int* in_sizes, int n_in,
                              void* d_out, int out_size, void* d_ws, size_t ws_size,
                              hipStream_t stream) {
    const float* x = (const float*)d_in[0];
    float* out = (float*)d_out;
    fps_part_kernel<<<BSZ * SEG, NLANES, 0, stream>>>(x, out);
}